// Round 11
// baseline (265.304 us; speedup 1.0000x reference)
//
#include <hip/hip_runtime.h>

// ReconPhongIF: Phong shading with ray-marched shadows.
// R12: refill hysteresis + same-ray unroll-4 (on R11's 102us base).
// R11 post-mortem: cursor+unroll-2 = 126.7->102us, VALU-equiv 55->49us
// (no unroll waste), stall 71->53us. Still ~50% stalled: (a) refill block
// runs ~every iteration (2-4 lane deaths/iter) and its dcache ds_read
// (~120cyc) + init chain stalls the wave; (b) one ~200cyc gather window
// per 2 steps. R12:
//  (1) hysteresis: refill only when >=16 lanes dead (or none active).
//      Dead lanes garbage-march harmlessly (NaN/inf -> float-clamp to valid
//      indices, proven safe in R10/R11); refill cost amortizes ~8x.
//  (2) unroll-4: 16 gathers in ONE latency window; exact-fallback hoisted
//      after all 4 fast paths; <=3 wasted steps per ray. krem 256%4==0.
// R7 XCD-pinned one-image-per-block mapping kept (FETCH 4MB, L1-resident).
// (R12 resubmission: previous round failed with GPUAcquisitionTimeout.)
// Ray decisions bit-identical to reference: sequential pos+=step fp32 adds
// (q[k]=q[k-1]+s), guarded rcp+Newton fast sample, exact-IEEE fallback
// inside the guard band; floor-exit (pz<=MDV) provably never flips a
// future/current test (sampled>=0.75 > pz+1e-6; convex-sum rounding <<1e-6).

#define SDIM 256
#define SS   (SDIM * SDIM)
#define TAN_T 0.08748866352592401      // tan(5 deg) in double
#define STEPC (2.0f / 255.0f)          // linspace(-1,1,256) step
#define POOL  1024                     // rays per block (4 rows)
#define WPOOL 256                      // rays per wave (1 row)
#define CPB   64                       // chunks per batch (64*1024 = 65536)
#define MDV   (0.75f - 1e-6f)          // early-exit floor (depth >= 0.75 by input domain)
#define RTHRESH 16                     // refill hysteresis: min dead lanes

// ---------------- exact fallback: bit-identical to reference ---------------
__device__ __forceinline__ bool shadow_exact(float px, float py, float pz,
                                             const float* __restrict__ im) {
#pragma clang fp contract(off)
    const float T = (float)TAN_T;
    const float gx = (px / pz) / T;
    const float gy = (py / pz) / T;
    const float x = (gx + 1.0f) * 128.0f - 0.5f;
    const float y = (gy + 1.0f) * 128.0f - 0.5f;
    const float xo = floorf(x), yo = floorf(y);
    const float wx = x - xo, wy = y - yo;
    const int ex0c = (int)fminf(fmaxf(xo,        0.0f), 255.0f);
    const int ex1c = (int)fminf(fmaxf(xo + 1.0f, 0.0f), 255.0f);
    const int ey0c = (int)fminf(fmaxf(yo,        0.0f), 255.0f);
    const int ey1c = (int)fminf(fmaxf(yo + 1.0f, 0.0f), 255.0f);
    const float e00 = im[(ey0c << 8) + ex0c];
    const float e01 = im[(ey0c << 8) + ex1c];
    const float e10 = im[(ey1c << 8) + ex0c];
    const float e11 = im[(ey1c << 8) + ex1c];
    float s = e00 * (1.0f - wx) * (1.0f - wy);
    s = s + e01 * wx * (1.0f - wy);
    s = s + e10 * (1.0f - wx) * wy;
    s = s + e11 * wx * wy;
    return (s - pz) < 0.0f;
}

// ------ quad-step fast test: 16 gathers in one window, fallback after ------
__device__ __forceinline__ void shadow_test4(const float* qx, const float* qy,
                                             const float* qz,
                                             const float* __restrict__ im,
                                             bool* h) {
#pragma clang fp contract(off)
    const float K = (float)(128.0 / TAN_T);
    float xf[4], yf[4], wx[4], wy[4];
    int i00[4], i01[4], i10[4], i11[4];
#pragma unroll
    for (int k = 0; k < 4; ++k) {
        float inv = __builtin_amdgcn_rcpf(qz[k]);
        inv = fmaf(fmaf(-qz[k], inv, 1.0f), inv, inv);
        xf[k] = fmaf(qx[k] * inv, K, 127.5f);
        yf[k] = fmaf(qy[k] * inv, K, 127.5f);
        const float x0f = floorf(xf[k]), y0f = floorf(yf[k]);
        wx[k] = xf[k] - x0f;
        wy[k] = yf[k] - y0f;
        // float-domain clamps (commute with reference int clamp; garbage-safe)
        const int x0c = (int)fminf(fmaxf(x0f,        0.0f), 255.0f);
        const int x1c = (int)fminf(fmaxf(x0f + 1.0f, 0.0f), 255.0f);
        const int y0c = (int)fminf(fmaxf(y0f,        0.0f), 255.0f);
        const int y1c = (int)fminf(fmaxf(y0f + 1.0f, 0.0f), 255.0f);
        i00[k] = (y0c << 8) + x0c;
        i01[k] = (y0c << 8) + x1c;
        i10[k] = (y1c << 8) + x0c;
        i11[k] = (y1c << 8) + x1c;
    }
    // all 16 loads issued back-to-back: one latency window
    float v00[4], v01[4], v10[4], v11[4];
#pragma unroll
    for (int k = 0; k < 4; ++k) {
        v00[k] = im[i00[k]];
        v01[k] = im[i01[k]];
        v10[k] = im[i10[k]];
        v11[k] = im[i11[k]];
    }
    float diff[4], grd[4];
    bool anyamb = false;
#pragma unroll
    for (int k = 0; k < 4; ++k) {
        const float omx = 1.0f - wx[k], omy = 1.0f - wy[k];
        const float t0 = fmaf(v01[k], wx[k], v00[k] * omx);
        const float t1 = fmaf(v11[k], wx[k], v10[k] * omx);
        const float sF = fmaf(t1, wy[k], t0 * omy);
        diff[k] = sF - qz[k];
        // guard: pos err ~3e-7*|coord|, Lipschitz ~0.5/px, 4x margin
        grd[k] = fmaf(fabsf(xf[k]) + fabsf(yf[k]), 6e-7f, 1e-5f);
        h[k] = diff[k] < 0.0f;
        anyamb = anyamb || (fabsf(diff[k]) <= grd[k]);
    }
    if (__builtin_expect(anyamb, 0)) {
#pragma unroll
        for (int k = 0; k < 4; ++k)
            if (fabsf(diff[k]) <= grd[k]) h[k] = shadow_exact(qx[k], qy[k], qz[k], im);
    }
}

// ---------------- stage 1: persistent march, wave-local pools --------------
__global__ __launch_bounds__(256) void shadow_march(const float* __restrict__ depth,
                                                    const float* __restrict__ light,
                                                    unsigned char* __restrict__ shmap) {
#pragma clang fp contract(off)
    // XCD-aware decode (validated R7: FETCH 47.5->4.1 MB): blk&7 -> XCD,
    // each XCD owns a contiguous group of 4 batches (1 MiB, L2-resident).
    const int blk   = blockIdx.x;
    const int xcd   = blk & 7;
    const int idx   = blk >> 3;            // 0..255 within XCD
    const int b     = (xcd << 2) | (idx >> 6);   // batch: 4 per XCD
    const int chunk = idx & (CPB - 1);     // chunk within batch
    const int rbase = chunk * POOL;        // ray offset within batch (4 rows)
    const float* im = depth + (size_t)b * SS;
    const int tid  = threadIdx.x;
    const int lane = tid & 63;
    const int wv   = tid >> 6;

    // per-batch params (uniform; exact reference op order)
    const float lx = light[b * 2 + 0];
    const float ly = light[b * 2 + 1];
    float n2 = lx * lx;
    n2 = n2 + ly * ly;
    n2 = n2 + 1.0f;
    const float nr = sqrtf(n2);
    const float sx = (-(lx / nr)) / 256.0f;
    const float sy = (-(ly / nr)) / 256.0f;
    const float sz = (-(1.0f / nr)) / 256.0f;
    const float T = (float)TAN_T;

    __shared__ float         dcache[POOL];
    __shared__ unsigned char res[POOL];
#pragma unroll
    for (int u = 0; u < POOL / 256; ++u) {
        const int r = tid + u * 256;
        dcache[r] = im[rbase + r];         // coalesced
    }
    __syncthreads();

    // ---- wave-local sequential pop (cursor wave-uniform; no atomics) ----
    const int wbase = wv << 8;             // this wave's 256-ray quarter (1 row)
    int cursor = 0;                        // uniform across the wave
    bool has = false, done = false;
    float px = 0.0f, py = 0.0f, pz = 1.0f;
    int rr = 0, krem = 0;

#pragma unroll 1
    while (true) {
        const bool need = (!has) && (!done);
        const unsigned long long mneed = __ballot(need);
        const unsigned long long mhas  = __ballot(has);
        // hysteresis: refill only when >=RTHRESH dead, or when none active
        if (mneed != 0ull &&
            (mhas == 0ull || (int)__popcll(mneed) >= RTHRESH)) {
            if (need) {
                const int prefix = (int)__popcll(mneed & ((1ull << (unsigned)lane) - 1ull));
                const int p = cursor + prefix;
                if (p < WPOOL) {
                    const int q = wbase + p;
                    const float d = dcache[q];
                    const int gidx = rbase + q;
                    const int i = gidx >> 8, j = gidx & 255;
                    const float cj = (-1.0f + (float)j * STEPC) * T;
                    const float ci = (-1.0f + (float)i * STEPC) * T;
                    px = cj * d; py = ci * d; pz = d;
                    rr = q; krem = 256; has = true;
                } else {
                    done = true;
                }
            }
            cursor += (int)__popcll(mneed);   // uniform update, all lanes
        }
        if (mhas == 0ull) {                   // only possible exit point
            if (__ballot(has) == 0ull) break;
        }

        // four sequential steps (bit-exact chain), tested together;
        // unconditional straight-line: dead lanes garbage-march safely
        float qx[4], qy[4], qz[4];
        qx[0] = px + sx;    qy[0] = py + sy;    qz[0] = pz + sz;
        qx[1] = qx[0] + sx; qy[1] = qy[0] + sy; qz[1] = qz[0] + sz;
        qx[2] = qx[1] + sx; qy[2] = qy[1] + sy; qz[2] = qz[1] + sz;
        qx[3] = qx[2] + sx; qy[3] = qy[2] + sy; qz[3] = qz[2] + sz;
        bool h[4];
        shadow_test4(qx, qy, qz, im, h);
        krem -= 4;
        if (has) {
            bool dead = true;
            unsigned char rv = 0;
            if      (qz[0] <= MDV) { rv = 0; }   // floor exit (exact, see hdr)
            else if (h[0])         { rv = 1; }
            else if (qz[1] <= MDV) { rv = 0; }
            else if (h[1])         { rv = 1; }
            else if (qz[2] <= MDV) { rv = 0; }
            else if (h[2])         { rv = 1; }
            else if (qz[3] <= MDV) { rv = 0; }
            else if (h[3])         { rv = 1; }
            else if (krem == 0)    { rv = 0; }
            else dead = false;
            if (dead) {
                res[rr] = rv;
                has = false;
                px = 0.0f; py = 0.0f; pz = 1.0f;   // benign dead-lane state
            } else {
                px = qx[3]; py = qy[3]; pz = qz[3];
            }
        } else {
            px = qx[3]; py = qy[3]; pz = qz[3];    // garbage march (safe)
        }
    }
    __syncthreads();
    // coalesced flush: 1024 result bytes = 256 dwords
    ((unsigned int*)(shmap + (size_t)b * SS + rbase))[tid] = ((const unsigned int*)res)[tid];
}

// ---------------- stage 2: blur + Phong composition ----------------
__device__ __constant__ float W1[7] = {
    0.07015933f, 0.13107488f, 0.19071282f, 0.21610594f,
    0.19071282f, 0.13107488f, 0.07015933f
};

__device__ __forceinline__ float fpow(float x, float p) {
    return __builtin_amdgcn_exp2f(p * __builtin_amdgcn_logf(x));
}
__device__ __forceinline__ float ftanh(float x) {
    const float e = __builtin_amdgcn_exp2f(x * 2.8853900817779268f);
    return (e - 1.0f) * __builtin_amdgcn_rcpf(e + 1.0f);
}

__global__ __launch_bounds__(256) void compose_kernel(const float* __restrict__ netA,
                                                      const float* __restrict__ netL,
                                                      const float* __restrict__ nrm,
                                                      const float* __restrict__ light,
                                                      const unsigned char* __restrict__ shmap,
                                                      float* __restrict__ out) {
    __shared__ float tile[22][23];

    const int b  = blockIdx.z;
    const int tx = threadIdx.x & 15;
    const int ty = threadIdx.x >> 4;
    const int j0 = blockIdx.x * 16;
    const int i0 = blockIdx.y * 16;

    const unsigned char* shb = shmap + (size_t)b * SS;
    for (int idx = threadIdx.x; idx < 22 * 22; idx += 256) {
        const int r = idx / 22, c = idx - r * 22;
        const int gi = i0 - 3 + r, gj = j0 - 3 + c;
        float v = 0.0f;
        if (gi >= 0 && gi < SDIM && gj >= 0 && gj < SDIM) v = (float)shb[gi * SDIM + gj];
        tile[r][c] = v;
    }
    __syncthreads();

    const int i = i0 + ty;
    const int j = j0 + tx;

    float shadow_s = 0.0f;
#pragma unroll
    for (int dy = 0; dy < 7; ++dy) {
        float rs = 0.0f;
#pragma unroll
        for (int dx = 0; dx < 7; ++dx) rs += W1[dx] * tile[ty + dy][tx + dx];
        shadow_s += W1[dy] * rs;
    }

    const float l0 = tanhf(netL[b * 6 + 0]);
    const float l1 = tanhf(netL[b * 6 + 1]);
    const float l2 = tanhf(netL[b * 6 + 2]);
    const float l5 = tanhf(netL[b * 6 + 5]);
    const float e  = l0 * 0.5f + 0.5f;
    const float f  = e * (float)10.313708498984761 + 1.0f;
    const float spec_alpha    = f * f;
    const float spec_strength = (l5 * 0.5f + 0.5f) * 0.5f;
    const float light_a = l1 / 2.0f + 0.5f;
    const float light_b = l2 / 2.0f + 0.5f;

    const float lx = light[b * 2 + 0];
    const float ly = light[b * 2 + 1];
    const float ln = sqrtf(lx * lx + ly * ly + 1.0f);
    const float ldx = lx / ln, ldy = ly / ln, ldz = 1.0f / ln;

    const float T = (float)TAN_T;
    const float xsj = (-1.0f + (float)(SDIM - 1 - j) * STEPC) * T;
    const float xsi = (-1.0f + (float)(SDIM - 1 - i) * STEPC) * T;
    const float vn = sqrtf(xsj * xsj + xsi * xsi + 1.0f);
    const float vd0 = xsj / vn, vd1 = xsi / vn, vd2 = 1.0f / vn;

    const size_t pix = (size_t)i * SDIM + j;
    const float n0 = nrm[((size_t)(b * 3 + 0)) * SS + pix];
    const float n1 = nrm[((size_t)(b * 3 + 1)) * SS + pix];
    const float n2 = nrm[((size_t)(b * 3 + 2)) * SS + pix];

    const float cos_t   = n0 * ldx + n1 * ldy + n2 * ldz;
    const float diffuse = fmaxf(cos_t, 0.0f);

    const float r0 = 2.0f * cos_t * n0 - ldx;
    const float r1 = 2.0f * cos_t * n1 - ldy;
    const float r2 = 2.0f * cos_t * n2 - ldz;
    float spec = fmaxf(vd0 * r0 + vd1 * r1 + vd2 * r2, 0.0f);
    const float gate  = (cos_t > 0.0f) ? 1.0f : 0.0f;
    const float maskv = (i >= 5 && i < SDIM - 5 && j >= 5 && j < SDIM - 5) ? 1.0f : 0.0f;
    spec = spec * gate * maskv;
    const float sclip = fminf(fmaxf(spec, 1e-7f), (float)(1.0 - 1e-7));
    const float sshad = fpow(sclip, spec_alpha);

    const float shadow_factor = fminf(fmaxf(1.0f - shadow_s, 0.1f), 1.0f);
    const float shading   = light_a + light_b * diffuse * shadow_factor;
    const float spec_term = spec_strength * light_b * sshad;

    const float inv_g = (float)(1.0 / 2.2);
#pragma unroll
    for (int c = 0; c < 3; ++c) {
        const float a   = netA[((size_t)(b * 5 + c)) * SS + pix];
        const float alb = fpow(ftanh(a) * 0.5f + 0.5f, 2.2f);
        float rim = alb * shading + spec_term;
        rim = fmaxf(rim, 1e-7f);
        out[((size_t)(b * 3 + c)) * SS + pix] = fpow(rim, inv_g);
    }
}

extern "C" void kernel_launch(void* const* d_in, const int* in_sizes, int n_in,
                              void* d_out, int out_size, void* d_ws, size_t ws_size,
                              hipStream_t stream) {
    const float* netA  = (const float*)d_in[0];
    const float* netL  = (const float*)d_in[1];
    const float* nrm   = (const float*)d_in[2];
    const float* depth = (const float*)d_in[3];
    const float* light = (const float*)d_in[4];
    float* out = (float*)d_out;

    unsigned char* shmap = (unsigned char*)d_ws;   // 2 MiB

    shadow_march<<<32 * CPB, 256, 0, stream>>>(depth, light, shmap);
    compose_kernel<<<dim3(SDIM / 16, SDIM / 16, 32), 256, 0, stream>>>(netA, netL, nrm,
                                                                       light, shmap, out);
}

// Round 14
// 209.928 us; speedup vs baseline: 1.2638x; 1.2638x over previous
//
#include <hip/hip_runtime.h>

// ReconPhongIF: Phong shading with ray-marched shadows.
// R13: march reverted to R11 exactly (102us known-good); compose restructured.
// R12 post-mortem: unroll-4 + hysteresis REGRESSED (157us): VALU-equiv 49->63us
// (garbage-march + overshoot waste) and stall 53->94us (16-value gather window
// at VGPR=36 forced load serialization). Reverted.
// Cross-round constant: total - march = 104-116us EVERY round = compose +
// overhead. R11 top-5 cutoff bounds compose <= 101.6us; roofline ~15us.
// R13 compose: 4 px/thread (float4 loads/stores, 2048 blocks, 32x32 tiles),
// per-batch uniforms amortized 4x, 38x40 halo tile. Per-pixel math BIT-
// IDENTICAL (same op order, same tanhf calls) -> absmax unchanged. This is
// an attribution experiment: total ~150-170 => compose was the cost;
// total >=205 => rest is harness overhead and we are at the floor.
// (R13 third submission: rounds 12 and 13 both failed with
// GPUAcquisitionTimeout before any kernel ran.)
// March: R11 = scalar per-wave pool cursor + same-ray unroll-2 fused dual
// test on R7's XCD-pinned per-block pools. Ray decisions bit-identical to
// reference (sequential fp32 adds, guarded rcp+Newton fast sample,
// exact-IEEE fallback in the guard band).

#define SDIM 256
#define SS   (SDIM * SDIM)
#define TAN_T 0.08748866352592401      // tan(5 deg) in double
#define STEPC (2.0f / 255.0f)          // linspace(-1,1,256) step
#define POOL  1024                     // rays per block (4 rows)
#define WPOOL 256                      // rays per wave (1 row)
#define CPB   64                       // chunks per batch (64*1024 = 65536)
#define MDV   (0.75f - 1e-6f)          // early-exit floor (depth >= 0.75 by input domain)

// ---------------- exact fallback: bit-identical to reference ---------------
__device__ __forceinline__ bool shadow_exact(float px, float py, float pz,
                                             const float* __restrict__ im) {
#pragma clang fp contract(off)
    const float T = (float)TAN_T;
    const float gx = (px / pz) / T;
    const float gy = (py / pz) / T;
    const float x = (gx + 1.0f) * 128.0f - 0.5f;
    const float y = (gy + 1.0f) * 128.0f - 0.5f;
    const float xo = floorf(x), yo = floorf(y);
    const float wx = x - xo, wy = y - yo;
    const int ex0c = (int)fminf(fmaxf(xo,        0.0f), 255.0f);
    const int ex1c = (int)fminf(fmaxf(xo + 1.0f, 0.0f), 255.0f);
    const int ey0c = (int)fminf(fmaxf(yo,        0.0f), 255.0f);
    const int ey1c = (int)fminf(fmaxf(yo + 1.0f, 0.0f), 255.0f);
    const float e00 = im[(ey0c << 8) + ex0c];
    const float e01 = im[(ey0c << 8) + ex1c];
    const float e10 = im[(ey1c << 8) + ex0c];
    const float e11 = im[(ey1c << 8) + ex1c];
    float s = e00 * (1.0f - wx) * (1.0f - wy);
    s = s + e01 * wx * (1.0f - wy);
    s = s + e10 * (1.0f - wx) * wy;
    s = s + e11 * wx * wy;
    return (s - pz) < 0.0f;
}

// -------- dual-step fast test: 8 gathers in one window, fallback after -----
__device__ __forceinline__ void shadow_test2(float px1, float py1, float pz1,
                                             float px2, float py2, float pz2,
                                             const float* __restrict__ im,
                                             bool& h1, bool& h2) {
#pragma clang fp contract(off)
    const float K = (float)(128.0 / TAN_T);
    float inv1 = __builtin_amdgcn_rcpf(pz1);
    inv1 = fmaf(fmaf(-pz1, inv1, 1.0f), inv1, inv1);
    float inv2 = __builtin_amdgcn_rcpf(pz2);
    inv2 = fmaf(fmaf(-pz2, inv2, 1.0f), inv2, inv2);
    const float xf1 = fmaf(px1 * inv1, K, 127.5f);
    const float yf1 = fmaf(py1 * inv1, K, 127.5f);
    const float xf2 = fmaf(px2 * inv2, K, 127.5f);
    const float yf2 = fmaf(py2 * inv2, K, 127.5f);
    const float x0f1 = floorf(xf1), y0f1 = floorf(yf1);
    const float x0f2 = floorf(xf2), y0f2 = floorf(yf2);
    const float wx1 = xf1 - x0f1, wy1 = yf1 - y0f1;
    const float wx2 = xf2 - x0f2, wy2 = yf2 - y0f2;
    // float-domain clamps (commute with reference int clamp; garbage-safe)
    const int x0c1 = (int)fminf(fmaxf(x0f1,        0.0f), 255.0f);
    const int x1c1 = (int)fminf(fmaxf(x0f1 + 1.0f, 0.0f), 255.0f);
    const int y0c1 = (int)fminf(fmaxf(y0f1,        0.0f), 255.0f);
    const int y1c1 = (int)fminf(fmaxf(y0f1 + 1.0f, 0.0f), 255.0f);
    const int x0c2 = (int)fminf(fmaxf(x0f2,        0.0f), 255.0f);
    const int x1c2 = (int)fminf(fmaxf(x0f2 + 1.0f, 0.0f), 255.0f);
    const int y0c2 = (int)fminf(fmaxf(y0f2,        0.0f), 255.0f);
    const int y1c2 = (int)fminf(fmaxf(y0f2 + 1.0f, 0.0f), 255.0f);
    const int r01 = y0c1 << 8, r11 = y1c1 << 8;
    const int r02 = y0c2 << 8, r12 = y1c2 << 8;
    // all 8 loads issued back-to-back: one latency window
    const float a00 = im[r01 + x0c1];
    const float a01 = im[r01 + x1c1];
    const float a10 = im[r11 + x0c1];
    const float a11 = im[r11 + x1c1];
    const float b00 = im[r02 + x0c2];
    const float b01 = im[r02 + x1c2];
    const float b10 = im[r12 + x0c2];
    const float b11 = im[r12 + x1c2];
    const float omx1 = 1.0f - wx1, omy1 = 1.0f - wy1;
    const float omx2 = 1.0f - wx2, omy2 = 1.0f - wy2;
    const float t0a = fmaf(a01, wx1, a00 * omx1);
    const float t1a = fmaf(a11, wx1, a10 * omx1);
    const float sa  = fmaf(t1a, wy1, t0a * omy1);
    const float t0b = fmaf(b01, wx2, b00 * omx2);
    const float t1b = fmaf(b11, wx2, b10 * omx2);
    const float sb  = fmaf(t1b, wy2, t0b * omy2);
    const float d1 = sa - pz1;
    const float d2 = sb - pz2;
    // guard: pos err ~3e-7*|coord|, Lipschitz ~0.5/px, 4x margin
    const float g1 = fmaf(fabsf(xf1) + fabsf(yf1), 6e-7f, 1e-5f);
    const float g2 = fmaf(fabsf(xf2) + fabsf(yf2), 6e-7f, 1e-5f);
    h1 = d1 < 0.0f;
    h2 = d2 < 0.0f;
    const bool amb1 = fabsf(d1) <= g1;
    const bool amb2 = fabsf(d2) <= g2;
    if (__builtin_expect(amb1 || amb2, 0)) {
        if (amb1) h1 = shadow_exact(px1, py1, pz1, im);
        if (amb2) h2 = shadow_exact(px2, py2, pz2, im);
    }
}

// ---------------- stage 1: persistent march, wave-local pools --------------
__global__ __launch_bounds__(256) void shadow_march(const float* __restrict__ depth,
                                                    const float* __restrict__ light,
                                                    unsigned char* __restrict__ shmap) {
#pragma clang fp contract(off)
    // XCD-aware decode (validated R7: FETCH 47.5->4.1 MB): blk&7 -> XCD,
    // each XCD owns a contiguous group of 4 batches (1 MiB, L2-resident).
    const int blk   = blockIdx.x;
    const int xcd   = blk & 7;
    const int idx   = blk >> 3;            // 0..255 within XCD
    const int b     = (xcd << 2) | (idx >> 6);   // batch: 4 per XCD
    const int chunk = idx & (CPB - 1);     // chunk within batch
    const int rbase = chunk * POOL;        // ray offset within batch (4 rows)
    const float* im = depth + (size_t)b * SS;
    const int tid  = threadIdx.x;
    const int lane = tid & 63;
    const int wv   = tid >> 6;

    // per-batch params (uniform; exact reference op order)
    const float lx = light[b * 2 + 0];
    const float ly = light[b * 2 + 1];
    float n2 = lx * lx;
    n2 = n2 + ly * ly;
    n2 = n2 + 1.0f;
    const float nr = sqrtf(n2);
    const float sx = (-(lx / nr)) / 256.0f;
    const float sy = (-(ly / nr)) / 256.0f;
    const float sz = (-(1.0f / nr)) / 256.0f;
    const float T = (float)TAN_T;

    __shared__ float         dcache[POOL];
    __shared__ unsigned char res[POOL];
#pragma unroll
    for (int u = 0; u < POOL / 256; ++u) {
        const int r = tid + u * 256;
        dcache[r] = im[rbase + r];         // coalesced
    }
    __syncthreads();

    // ---- wave-local sequential pop (cursor is wave-uniform: no atomics) ----
    const int wbase = wv << 8;             // this wave's 256-ray quarter (1 row)
    int cursor = 0;                        // uniform across the wave
    bool has = false, done = false;
    float px = 0.0f, py = 0.0f, pz = 1.0f;
    int rr = 0, krem = 0;

#pragma unroll 1
    while (true) {
        const bool need = (!has) && (!done);
        const unsigned long long mneed = __ballot(need);
        if (mneed != 0ull) {               // wave-uniform branch
            if (need) {
                const int prefix = (int)__popcll(mneed & ((1ull << (unsigned)lane) - 1ull));
                const int p = cursor + prefix;
                if (p < WPOOL) {
                    const int q = wbase + p;
                    const float d = dcache[q];
                    const int gidx = rbase + q;
                    const int i = gidx >> 8, j = gidx & 255;
                    const float cj = (-1.0f + (float)j * STEPC) * T;
                    const float ci = (-1.0f + (float)i * STEPC) * T;
                    px = cj * d; py = ci * d; pz = d;
                    rr = q; krem = 256; has = true;
                } else {
                    done = true;
                }
            }
            cursor += (int)__popcll(mneed);   // uniform update, all lanes
        }
        if (__ballot(has) == 0ull) break;
        if (has) {
            // two sequential steps (bit-exact chain), tested together
            const float px1 = px + sx, py1 = py + sy, pz1 = pz + sz;
            const float px2 = px1 + sx, py2 = py1 + sy, pz2 = pz1 + sz;
            bool h1, h2;
            shadow_test2(px1, py1, pz1, px2, py2, pz2, im, h1, h2);
            const bool fl1 = pz1 <= MDV;   // exact early-exit floor
            const bool fl2 = pz2 <= MDV;
            krem -= 2;
            bool dead = true;
            unsigned char rv = 0;
            if      (fl1)       { rv = 0; }
            else if (h1)        { rv = 1; }
            else if (fl2)       { rv = 0; }
            else if (h2)        { rv = 1; }
            else if (krem == 0) { rv = 0; }
            else dead = false;
            if (dead) {
                res[rr] = rv;
                has = false;
                px = 0.0f; py = 0.0f; pz = 1.0f;   // benign dead-lane state
            } else {
                px = px2; py = py2; pz = pz2;
            }
        }
    }
    __syncthreads();
    // coalesced flush: 1024 result bytes = 256 dwords
    ((unsigned int*)(shmap + (size_t)b * SS + rbase))[tid] = ((const unsigned int*)res)[tid];
}

// ---------------- stage 2: blur + Phong composition (4 px/thread) ----------
__device__ __constant__ float W1[7] = {
    0.07015933f, 0.13107488f, 0.19071282f, 0.21610594f,
    0.19071282f, 0.13107488f, 0.07015933f
};

__device__ __forceinline__ float fpow(float x, float p) {
    return __builtin_amdgcn_exp2f(p * __builtin_amdgcn_logf(x));
}
__device__ __forceinline__ float ftanh(float x) {
    const float e = __builtin_amdgcn_exp2f(x * 2.8853900817779268f);
    return (e - 1.0f) * __builtin_amdgcn_rcpf(e + 1.0f);
}

__global__ __launch_bounds__(256) void compose_kernel(const float* __restrict__ netA,
                                                      const float* __restrict__ netL,
                                                      const float* __restrict__ nrm,
                                                      const float* __restrict__ light,
                                                      const unsigned char* __restrict__ shmap,
                                                      float* __restrict__ out) {
    __shared__ float tile[38][40];         // 32x32 output + 7x7 blur halo

    const int b   = blockIdx.z;
    const int j0  = blockIdx.x * 32;
    const int i0  = blockIdx.y * 32;
    const int tid = threadIdx.x;

    const unsigned char* shb = shmap + (size_t)b * SS;
#pragma unroll
    for (int u = 0; u < 6; ++u) {          // 6*256 = 1536 >= 38*40 = 1520
        const int idx = tid + u * 256;
        if (idx < 38 * 40) {
            const int r = idx / 40, c = idx - r * 40;
            float v = 0.0f;
            const int gi = i0 - 3 + r, gj = j0 - 3 + c;
            if (c < 38 && gi >= 0 && gi < SDIM && gj >= 0 && gj < SDIM)
                v = (float)shb[gi * SDIM + gj];
            tile[r][c] = v;
        }
    }
    __syncthreads();

    const int ty = tid >> 3;               // 0..31 (row within tile)
    const int tx = (tid & 7) << 2;         // 0,4,..,28 (4 consecutive cols)
    const int i  = i0 + ty;

    // per-batch uniforms (bit-identical op order; amortized over 4 px)
    const float l0 = tanhf(netL[b * 6 + 0]);
    const float l1 = tanhf(netL[b * 6 + 1]);
    const float l2 = tanhf(netL[b * 6 + 2]);
    const float l5 = tanhf(netL[b * 6 + 5]);
    const float e  = l0 * 0.5f + 0.5f;
    const float f  = e * (float)10.313708498984761 + 1.0f;
    const float spec_alpha    = f * f;
    const float spec_strength = (l5 * 0.5f + 0.5f) * 0.5f;
    const float light_a = l1 / 2.0f + 0.5f;
    const float light_b = l2 / 2.0f + 0.5f;

    const float lx = light[b * 2 + 0];
    const float ly = light[b * 2 + 1];
    const float ln = sqrtf(lx * lx + ly * ly + 1.0f);
    const float ldx = lx / ln, ldy = ly / ln, ldz = 1.0f / ln;

    const float T = (float)TAN_T;
    const float xsi = (-1.0f + (float)(SDIM - 1 - i) * STEPC) * T;

    // vectorized loads: 4 consecutive pixels (16B/lane, coalesced)
    const size_t pix = (size_t)i * SDIM + j0 + tx;
    const float4 nv0 = *(const float4*)&nrm[((size_t)(b * 3 + 0)) * SS + pix];
    const float4 nv1 = *(const float4*)&nrm[((size_t)(b * 3 + 1)) * SS + pix];
    const float4 nv2 = *(const float4*)&nrm[((size_t)(b * 3 + 2)) * SS + pix];
    const float4 av0 = *(const float4*)&netA[((size_t)(b * 5 + 0)) * SS + pix];
    const float4 av1 = *(const float4*)&netA[((size_t)(b * 5 + 1)) * SS + pix];
    const float4 av2 = *(const float4*)&netA[((size_t)(b * 5 + 2)) * SS + pix];
    const float n0a[4] = {nv0.x, nv0.y, nv0.z, nv0.w};
    const float n1a[4] = {nv1.x, nv1.y, nv1.z, nv1.w};
    const float n2a[4] = {nv2.x, nv2.y, nv2.z, nv2.w};
    const float a0a[4] = {av0.x, av0.y, av0.z, av0.w};
    const float a1a[4] = {av1.x, av1.y, av1.z, av1.w};
    const float a2a[4] = {av2.x, av2.y, av2.z, av2.w};

    float o0[4], o1[4], o2[4];
    const float inv_g = (float)(1.0 / 2.2);

#pragma unroll
    for (int u = 0; u < 4; ++u) {
        const int j = j0 + tx + u;

        // blur: identical FMA order to the 16x16 version (bit-identical)
        float shadow_s = 0.0f;
#pragma unroll
        for (int dy = 0; dy < 7; ++dy) {
            float rs = 0.0f;
#pragma unroll
            for (int dx = 0; dx < 7; ++dx) rs += W1[dx] * tile[ty + dy][tx + u + dx];
            shadow_s += W1[dy] * rs;
        }

        const float xsj = (-1.0f + (float)(SDIM - 1 - j) * STEPC) * T;
        const float vn = sqrtf(xsj * xsj + xsi * xsi + 1.0f);
        const float vd0 = xsj / vn, vd1 = xsi / vn, vd2 = 1.0f / vn;

        const float n0 = n0a[u], n1 = n1a[u], n2 = n2a[u];
        const float cos_t   = n0 * ldx + n1 * ldy + n2 * ldz;
        const float diffuse = fmaxf(cos_t, 0.0f);

        const float r0 = 2.0f * cos_t * n0 - ldx;
        const float r1 = 2.0f * cos_t * n1 - ldy;
        const float r2 = 2.0f * cos_t * n2 - ldz;
        float spec = fmaxf(vd0 * r0 + vd1 * r1 + vd2 * r2, 0.0f);
        const float gate  = (cos_t > 0.0f) ? 1.0f : 0.0f;
        const float maskv = (i >= 5 && i < SDIM - 5 && j >= 5 && j < SDIM - 5) ? 1.0f : 0.0f;
        spec = spec * gate * maskv;
        const float sclip = fminf(fmaxf(spec, 1e-7f), (float)(1.0 - 1e-7));
        const float sshad = fpow(sclip, spec_alpha);

        const float shadow_factor = fminf(fmaxf(1.0f - shadow_s, 0.1f), 1.0f);
        const float shading   = light_a + light_b * diffuse * shadow_factor;
        const float spec_term = spec_strength * light_b * sshad;

        const float alb0 = fpow(ftanh(a0a[u]) * 0.5f + 0.5f, 2.2f);
        const float alb1 = fpow(ftanh(a1a[u]) * 0.5f + 0.5f, 2.2f);
        const float alb2 = fpow(ftanh(a2a[u]) * 0.5f + 0.5f, 2.2f);
        o0[u] = fpow(fmaxf(alb0 * shading + spec_term, 1e-7f), inv_g);
        o1[u] = fpow(fmaxf(alb1 * shading + spec_term, 1e-7f), inv_g);
        o2[u] = fpow(fmaxf(alb2 * shading + spec_term, 1e-7f), inv_g);
    }

    // vectorized stores
    *(float4*)&out[((size_t)(b * 3 + 0)) * SS + pix] = make_float4(o0[0], o0[1], o0[2], o0[3]);
    *(float4*)&out[((size_t)(b * 3 + 1)) * SS + pix] = make_float4(o1[0], o1[1], o1[2], o1[3]);
    *(float4*)&out[((size_t)(b * 3 + 2)) * SS + pix] = make_float4(o2[0], o2[1], o2[2], o2[3]);
}

extern "C" void kernel_launch(void* const* d_in, const int* in_sizes, int n_in,
                              void* d_out, int out_size, void* d_ws, size_t ws_size,
                              hipStream_t stream) {
    const float* netA  = (const float*)d_in[0];
    const float* netL  = (const float*)d_in[1];
    const float* nrm   = (const float*)d_in[2];
    const float* depth = (const float*)d_in[3];
    const float* light = (const float*)d_in[4];
    float* out = (float*)d_out;

    unsigned char* shmap = (unsigned char*)d_ws;   // 2 MiB

    shadow_march<<<32 * CPB, 256, 0, stream>>>(depth, light, shmap);
    compose_kernel<<<dim3(SDIM / 32, SDIM / 32, 32), 256, 0, stream>>>(netA, netL, nrm,
                                                                       light, shmap, out);
}